// Round 5
// baseline (240.385 us; speedup 1.0000x reference)
//
#include <hip/hip_runtime.h>
#include <cstdint>
#include <cstddef>

#define LALPHA 0.2f
#define NEG_INF -9000000000000000.0f

constexpr int N_ = 1024;
constexpr int FIN = 128, FO = 64;
constexpr int BS = 32;
constexpr size_t H_ELEMS = (size_t)BS * N_ * FO;   // 2,097,152
constexpr size_t F_ELEMS = (size_t)BS * N_;        // 32,768
constexpr int SPLITK = 8;                          // j-range chunks (128 j each)

typedef __attribute__((ext_vector_type(8))) short short8;
typedef __attribute__((ext_vector_type(4))) float floatx4;

static __device__ __forceinline__ unsigned short f2bf(float x) {
    union { float f; unsigned u; } v; v.f = x;
    unsigned r = v.u + 0x7FFF + ((v.u >> 16) & 1);
    return (unsigned short)(r >> 16);
}
static __device__ __forceinline__ float bf2f_lo(unsigned u) {
    union { unsigned u; float f; } v; v.u = u << 16; return v.f;
}
static __device__ __forceinline__ float bf2f_hi(unsigned u) {
    union { unsigned u; float f; } v; v.u = u & 0xFFFF0000u; return v.f;
}

// ---------------- Kernel 1: h = x @ W, f1 = h@a1, f2 = h@a2 ----------------
__global__ __launch_bounds__(256) void k_h(
    const float* __restrict__ x, const float* __restrict__ W,
    const float* __restrict__ a, float* __restrict__ h,
    float* __restrict__ f1, float* __restrict__ f2)
{
    __shared__ float sW[FIN * FO];     // 32 KB
    __shared__ float sx[4][FIN];       // 2 KB
    const int t = threadIdx.x;
    for (int i = t; i < FIN * FO; i += 256) sW[i] = W[i];
    const size_t node0 = (size_t)blockIdx.x * 4;
    for (int i = t; i < 4 * FIN; i += 256) sx[i >> 7][i & 127] = x[node0 * FIN + i];
    __syncthreads();

    const int wave = t >> 6;
    const int lane = t & 63;
    const size_t node = node0 + wave;

    float acc = 0.f;
    #pragma unroll
    for (int f = 0; f < FIN; ++f)
        acc = fmaf(sx[wave][f], sW[f * FO + lane], acc);

    h[node * FO + lane] = acc;

    float v1 = acc * a[lane];
    float v2 = acc * a[FO + lane];
    #pragma unroll
    for (int off = 32; off > 0; off >>= 1) {
        v1 += __shfl_xor(v1, off);
        v2 += __shfl_xor(v2, off);
    }
    if (lane == 0) { f1[node] = v1; f2[node] = v2; }
}

// ------------- Kernel 2: transpose+convert h -> hT bf16 [bs][o][j] ----------
__global__ __launch_bounds__(256) void k_tr(
    const float* __restrict__ h, unsigned short* __restrict__ hT)
{
    __shared__ float lt[64][65];
    const int bs = blockIdx.x >> 4;
    const int n0 = (blockIdx.x & 15) * 64;
    const int t = threadIdx.x;
    const float* hb = h + ((size_t)bs << 16) + ((size_t)n0 << 6);
    #pragma unroll
    for (int k = 0; k < 4; ++k) {
        const int r = (t >> 4) + k * 16;
        const int c = (t & 15) * 4;
        const float4 v = *(const float4*)(hb + ((size_t)r << 6) + c);
        lt[r][c] = v.x; lt[r][c + 1] = v.y; lt[r][c + 2] = v.z; lt[r][c + 3] = v.w;
    }
    __syncthreads();
    const int o = t >> 2, ch = (t & 3) * 16;
    unsigned short tmp[16];
    #pragma unroll
    for (int q = 0; q < 16; ++q) tmp[q] = f2bf(lt[ch + q][o]);
    unsigned short* dst = hT + ((size_t)bs << 16) + ((size_t)o << 10) + n0 + ch;
    *(uint4*)dst = *(uint4*)tmp;
    *(uint4*)(dst + 8) = *(uint4*)(tmp + 8);
}

// ---- Kernel 3: fused softmax-over-s + adjf copy + MFMA att@h (split-K) ----
// block: (kk, b, 16-row i-tile); handles j range [kk*128, kk*128+128).
// TLP latency hiding: SPLITK=8 -> 2048 blocks -> 8 blocks/CU (32 waves/CU).
__global__ __launch_bounds__(256, 8) void k_av(
    const int* __restrict__ Adj, const float* __restrict__ f1,
    const float* __restrict__ f2, const unsigned short* __restrict__ hT,
    unsigned short* __restrict__ part, float* __restrict__ out_adj)
{
    __shared__ __align__(16) unsigned short att[8][16][64];   // 16 KB

    const int bid   = blockIdx.x;
    const int kk    = bid >> 8;          // 0..7
    const int b     = (bid >> 6) & 3;
    const int i0    = (bid & 63) * 16;
    const int t     = threadIdx.x;

    const int p_jj = (t & 15) * 4;
    const int p_ii = t >> 4;
    const int gi   = i0 + p_ii;

    const int w  = t >> 6;
    const int l  = t & 63;
    const int fr = l & 15;
    const int fg = l >> 4;

    float fi[8];
    #pragma unroll
    for (int s = 0; s < 8; ++s) fi[s] = f1[(size_t)(b * 8 + s) * N_ + gi];

    floatx4 acc[2][4];
    #pragma unroll
    for (int si = 0; si < 2; ++si)
        #pragma unroll
        for (int n = 0; n < 4; ++n)
            acc[si][n] = (floatx4){0.f, 0.f, 0.f, 0.f};

    for (int jt = 0; jt < 2; ++jt) {
        const int j0 = (kk * 2 + jt) * 64;

        // ---- phase 1: issue all Adj loads first (MLP), then softmax ----
        int4 ad[8];
        #pragma unroll
        for (int s = 0; s < 8; ++s) {
            const size_t aoff = ((size_t)(b * 8 + s) << 20) + ((size_t)gi << 10) + (size_t)(j0 + p_jj);
            ad[s] = *(const int4*)(Adj + aoff);
        }
        float ev[8][4];
        #pragma unroll
        for (int s = 0; s < 8; ++s) {
            const size_t aoff = ((size_t)(b * 8 + s) << 20) + ((size_t)gi << 10) + (size_t)(j0 + p_jj);
            *(float4*)(out_adj + aoff) =
                make_float4((float)ad[s].x, (float)ad[s].y, (float)ad[s].z, (float)ad[s].w);
            const float4 fj = *(const float4*)(f2 + (size_t)(b * 8 + s) * N_ + j0 + p_jj);
            const float v0 = fi[s] + fj.x, v1 = fi[s] + fj.y;
            const float v2 = fi[s] + fj.z, v3 = fi[s] + fj.w;
            ev[s][0] = ad[s].x > 0 ? (v0 >= 0.f ? v0 : LALPHA * v0) : NEG_INF;
            ev[s][1] = ad[s].y > 0 ? (v1 >= 0.f ? v1 : LALPHA * v1) : NEG_INF;
            ev[s][2] = ad[s].z > 0 ? (v2 >= 0.f ? v2 : LALPHA * v2) : NEG_INF;
            ev[s][3] = ad[s].w > 0 ? (v3 >= 0.f ? v3 : LALPHA * v3) : NEG_INF;
        }
        #pragma unroll
        for (int q = 0; q < 4; ++q) {
            float m = NEG_INF;
            #pragma unroll
            for (int s = 0; s < 8; ++s) m = fmaxf(m, ev[s][q]);
            float p[8], den = 0.f;
            #pragma unroll
            for (int s = 0; s < 8; ++s) { p[s] = __expf(ev[s][q] - m); den += p[s]; }
            const float r = 1.0f / den;
            #pragma unroll
            for (int s = 0; s < 8; ++s) ev[s][q] = p[s] * r;
        }
        {
            const int chs  = (p_jj >> 3) ^ (p_ii & 7);
            const int boff = chs * 16 + (p_jj & 7) * 2;
            #pragma unroll
            for (int s = 0; s < 8; ++s) {
                ushort4 wv;
                wv.x = f2bf(ev[s][0]); wv.y = f2bf(ev[s][1]);
                wv.z = f2bf(ev[s][2]); wv.w = f2bf(ev[s][3]);
                *(ushort4*)((char*)&att[s][p_ii][0] + boff) = wv;
            }
        }
        __syncthreads();

        // ---- phase 2: MFMA ----
        #pragma unroll
        for (int ks = 0; ks < 2; ++ks) {
            short8 af[2];
            #pragma unroll
            for (int si = 0; si < 2; ++si) {
                const int s = 2 * w + si;
                const int c = (ks * 4 + fg) ^ (fr & 7);
                af[si] = *(const short8*)((const char*)&att[s][fr][0] + c * 16);
            }
            #pragma unroll
            for (int n = 0; n < 4; ++n) {
                #pragma unroll
                for (int si = 0; si < 2; ++si) {
                    const int bs = b * 8 + 2 * w + si;
                    const short8 bf = *(const short8*)(
                        hT + ((size_t)bs << 16) + (size_t)(n * 16 + fr) * N_ + j0 + ks * 32 + fg * 8);
                    acc[si][n] = __builtin_amdgcn_mfma_f32_16x16x32_bf16(af[si], bf, acc[si][n], 0, 0, 0);
                }
            }
        }
        __syncthreads();
    }

    // ---- epilogue: write bf16 partials (no elu) ----
    #pragma unroll
    for (int si = 0; si < 2; ++si) {
        const int bs = b * 8 + 2 * w + si;
        #pragma unroll
        for (int n = 0; n < 4; ++n) {
            #pragma unroll
            for (int r = 0; r < 4; ++r) {
                part[(size_t)kk * H_ELEMS + ((size_t)bs << 16)
                     + (size_t)(i0 + fg * 4 + r) * FO + n * 16 + fr] = f2bf(acc[si][n][r]);
            }
        }
    }
}

// ---------------- Kernel 4: combine 8 bf16 partials + elu -------------------
__global__ __launch_bounds__(256) void k_comb(
    const unsigned short* __restrict__ part, float* __restrict__ out_h)
{
    const size_t idx = ((size_t)blockIdx.x * 256 + threadIdx.x) * 8;
    float acc[8] = {0.f,0.f,0.f,0.f,0.f,0.f,0.f,0.f};
    #pragma unroll
    for (int p = 0; p < SPLITK; ++p) {
        const uint4 v = *(const uint4*)(part + (size_t)p * H_ELEMS + idx);
        acc[0] += bf2f_lo(v.x); acc[1] += bf2f_hi(v.x);
        acc[2] += bf2f_lo(v.y); acc[3] += bf2f_hi(v.y);
        acc[4] += bf2f_lo(v.z); acc[5] += bf2f_hi(v.z);
        acc[6] += bf2f_lo(v.w); acc[7] += bf2f_hi(v.w);
    }
    float4 r0, r1;
    r0.x = acc[0] > 0.f ? acc[0] : expm1f(acc[0]);
    r0.y = acc[1] > 0.f ? acc[1] : expm1f(acc[1]);
    r0.z = acc[2] > 0.f ? acc[2] : expm1f(acc[2]);
    r0.w = acc[3] > 0.f ? acc[3] : expm1f(acc[3]);
    r1.x = acc[4] > 0.f ? acc[4] : expm1f(acc[4]);
    r1.y = acc[5] > 0.f ? acc[5] : expm1f(acc[5]);
    r1.z = acc[6] > 0.f ? acc[6] : expm1f(acc[6]);
    r1.w = acc[7] > 0.f ? acc[7] : expm1f(acc[7]);
    *(float4*)(out_h + idx) = r0;
    *(float4*)(out_h + idx + 4) = r1;
}

extern "C" void kernel_launch(void* const* d_in, const int* in_sizes, int n_in,
                              void* d_out, int out_size, void* d_ws, size_t ws_size,
                              hipStream_t stream)
{
    const float* x   = (const float*)d_in[0];
    const int*   Adj = (const int*)d_in[1];
    const float* W   = (const float*)d_in[2];
    const float* a   = (const float*)d_in[3];

    float* out = (float*)d_out;
    float* ws  = (float*)d_ws;

    // ws layout (f32 slots): f1 | f2 | hT(bf16) | h(f32) / part(bf16, aliased)
    float* f1 = ws;                                   // 32,768
    float* f2 = f1 + F_ELEMS;                         // 32,768
    unsigned short* hT = (unsigned short*)(f2 + F_ELEMS);   // H_ELEMS bf16 (4 MB)
    float* h = f2 + F_ELEMS + H_ELEMS / 2;            // 8 MB f32 (dead after k_tr)
    unsigned short* part = (unsigned short*)h;        // 8*H_ELEMS bf16 = 32 MB

    float* out_h   = out;                             // elu(h_prime)
    float* out_adj = out + H_ELEMS;                   // Adj as float

    hipLaunchKernelGGL(k_h,    dim3(BS * N_ / 4),           dim3(256), 0, stream, x, W, a, h, f1, f2);
    hipLaunchKernelGGL(k_tr,   dim3(BS * 16),               dim3(256), 0, stream, h, hT);
    hipLaunchKernelGGL(k_av,   dim3(SPLITK * 4 * 64),       dim3(256), 0, stream, Adj, f1, f2, hT, part, out_adj);
    hipLaunchKernelGGL(k_comb, dim3((int)(H_ELEMS / 2048)), dim3(256), 0, stream, part, out_h);
}

// Round 6
// 153.578 us; speedup vs baseline: 1.5652x; 1.5652x over previous
//
#include <hip/hip_runtime.h>
#include <cstdint>
#include <cstddef>

#define LALPHA 0.2f
#define NEG_INF -9000000000000000.0f

constexpr int N_ = 1024;
constexpr int FIN = 128, FO = 64;
constexpr int BS = 32;
constexpr size_t H_ELEMS = (size_t)BS * N_ * FO;   // 2,097,152
constexpr size_t F_ELEMS = (size_t)BS * N_;        // 32,768
constexpr int SPLITK = 8;                          // j-range chunks (128 j each)

typedef __attribute__((ext_vector_type(8))) short short8;
typedef __attribute__((ext_vector_type(4))) float floatx4;

static __device__ __forceinline__ unsigned short f2bf(float x) {
    union { float f; unsigned u; } v; v.f = x;
    unsigned r = v.u + 0x7FFF + ((v.u >> 16) & 1);
    return (unsigned short)(r >> 16);
}
static __device__ __forceinline__ float bf2f_lo(unsigned u) {
    union { unsigned u; float f; } v; v.u = u << 16; return v.f;
}
static __device__ __forceinline__ float bf2f_hi(unsigned u) {
    union { unsigned u; float f; } v; v.u = u & 0xFFFF0000u; return v.f;
}

// ---------------- Kernel 1: h = x @ W, f1 = h@a1, f2 = h@a2 ----------------
__global__ __launch_bounds__(256) void k_h(
    const float* __restrict__ x, const float* __restrict__ W,
    const float* __restrict__ a, float* __restrict__ h,
    float* __restrict__ f1, float* __restrict__ f2)
{
    __shared__ float sW[FIN * FO];     // 32 KB
    __shared__ float sx[4][FIN];       // 2 KB
    const int t = threadIdx.x;
    for (int i = t; i < FIN * FO; i += 256) sW[i] = W[i];
    const size_t node0 = (size_t)blockIdx.x * 4;
    for (int i = t; i < 4 * FIN; i += 256) sx[i >> 7][i & 127] = x[node0 * FIN + i];
    __syncthreads();

    const int wave = t >> 6;
    const int lane = t & 63;
    const size_t node = node0 + wave;

    float acc = 0.f;
    #pragma unroll
    for (int f = 0; f < FIN; ++f)
        acc = fmaf(sx[wave][f], sW[f * FO + lane], acc);

    h[node * FO + lane] = acc;

    float v1 = acc * a[lane];
    float v2 = acc * a[FO + lane];
    #pragma unroll
    for (int off = 32; off > 0; off >>= 1) {
        v1 += __shfl_xor(v1, off);
        v2 += __shfl_xor(v2, off);
    }
    if (lane == 0) { f1[node] = v1; f2[node] = v2; }
}

// ------------- Kernel 2: transpose+convert h -> hT bf16 [bs][o][j] ----------
__global__ __launch_bounds__(256) void k_tr(
    const float* __restrict__ h, unsigned short* __restrict__ hT)
{
    __shared__ float lt[64][65];
    const int bs = blockIdx.x >> 4;
    const int n0 = (blockIdx.x & 15) * 64;
    const int t = threadIdx.x;
    const float* hb = h + ((size_t)bs << 16) + ((size_t)n0 << 6);
    #pragma unroll
    for (int k = 0; k < 4; ++k) {
        const int r = (t >> 4) + k * 16;
        const int c = (t & 15) * 4;
        const float4 v = *(const float4*)(hb + ((size_t)r << 6) + c);
        lt[r][c] = v.x; lt[r][c + 1] = v.y; lt[r][c + 2] = v.z; lt[r][c + 3] = v.w;
    }
    __syncthreads();
    const int o = t >> 2, ch = (t & 3) * 16;
    unsigned short tmp[16];
    #pragma unroll
    for (int q = 0; q < 16; ++q) tmp[q] = f2bf(lt[ch + q][o]);
    unsigned short* dst = hT + ((size_t)bs << 16) + ((size_t)o << 10) + n0 + ch;
    *(uint4*)dst = *(uint4*)tmp;
    *(uint4*)(dst + 8) = *(uint4*)(tmp + 8);
}

// ---- Kernel 3: fused softmax-over-s + adjf copy + MFMA att@h (split-K) ----
// block: (kk, b, 16-row i-tile); handles j range [kk*128, kk*128+128).
// SPLITK=8 -> 2048 blocks -> up to 8 blocks/CU. launch_bounds(256,4) (NOT 8):
// the allocator floor stays at 4 so it keeps 64 VGPR (no spill); HW occupancy
// still reaches 8 blocks/CU since 64 VGPR allows 8 waves/SIMD.
__global__ __launch_bounds__(256, 4) void k_av(
    const int* __restrict__ Adj, const float* __restrict__ f1,
    const float* __restrict__ f2, const unsigned short* __restrict__ hT,
    unsigned short* __restrict__ part, float* __restrict__ out_adj)
{
    __shared__ __align__(16) unsigned short att[8][16][64];   // 16 KB

    const int bid   = blockIdx.x;
    const int kk    = bid >> 8;          // 0..7
    const int b     = (bid >> 6) & 3;
    const int i0    = (bid & 63) * 16;
    const int t     = threadIdx.x;

    const int p_jj = (t & 15) * 4;
    const int p_ii = t >> 4;
    const int gi   = i0 + p_ii;

    const int w  = t >> 6;
    const int l  = t & 63;
    const int fr = l & 15;
    const int fg = l >> 4;

    float fi[8];
    #pragma unroll
    for (int s = 0; s < 8; ++s) fi[s] = f1[(size_t)(b * 8 + s) * N_ + gi];

    floatx4 acc[2][4];
    #pragma unroll
    for (int si = 0; si < 2; ++si)
        #pragma unroll
        for (int n = 0; n < 4; ++n)
            acc[si][n] = (floatx4){0.f, 0.f, 0.f, 0.f};

    for (int jt = 0; jt < 2; ++jt) {
        const int j0 = (kk * 2 + jt) * 64;

        // ---- phase 1: issue all Adj loads first (MLP), then softmax ----
        int4 ad[8];
        #pragma unroll
        for (int s = 0; s < 8; ++s) {
            const size_t aoff = ((size_t)(b * 8 + s) << 20) + ((size_t)gi << 10) + (size_t)(j0 + p_jj);
            ad[s] = *(const int4*)(Adj + aoff);
        }
        float ev[8][4];
        #pragma unroll
        for (int s = 0; s < 8; ++s) {
            const size_t aoff = ((size_t)(b * 8 + s) << 20) + ((size_t)gi << 10) + (size_t)(j0 + p_jj);
            *(float4*)(out_adj + aoff) =
                make_float4((float)ad[s].x, (float)ad[s].y, (float)ad[s].z, (float)ad[s].w);
            const float4 fj = *(const float4*)(f2 + (size_t)(b * 8 + s) * N_ + j0 + p_jj);
            const float v0 = fi[s] + fj.x, v1 = fi[s] + fj.y;
            const float v2 = fi[s] + fj.z, v3 = fi[s] + fj.w;
            ev[s][0] = ad[s].x > 0 ? (v0 >= 0.f ? v0 : LALPHA * v0) : NEG_INF;
            ev[s][1] = ad[s].y > 0 ? (v1 >= 0.f ? v1 : LALPHA * v1) : NEG_INF;
            ev[s][2] = ad[s].z > 0 ? (v2 >= 0.f ? v2 : LALPHA * v2) : NEG_INF;
            ev[s][3] = ad[s].w > 0 ? (v3 >= 0.f ? v3 : LALPHA * v3) : NEG_INF;
        }
        #pragma unroll
        for (int q = 0; q < 4; ++q) {
            float m = NEG_INF;
            #pragma unroll
            for (int s = 0; s < 8; ++s) m = fmaxf(m, ev[s][q]);
            float p[8], den = 0.f;
            #pragma unroll
            for (int s = 0; s < 8; ++s) { p[s] = __expf(ev[s][q] - m); den += p[s]; }
            const float r = 1.0f / den;
            #pragma unroll
            for (int s = 0; s < 8; ++s) ev[s][q] = p[s] * r;
        }
        {
            const int chs  = (p_jj >> 3) ^ (p_ii & 7);
            const int boff = chs * 16 + (p_jj & 7) * 2;
            #pragma unroll
            for (int s = 0; s < 8; ++s) {
                ushort4 wv;
                wv.x = f2bf(ev[s][0]); wv.y = f2bf(ev[s][1]);
                wv.z = f2bf(ev[s][2]); wv.w = f2bf(ev[s][3]);
                *(ushort4*)((char*)&att[s][p_ii][0] + boff) = wv;
            }
        }
        __syncthreads();

        // ---- phase 2: MFMA ----
        #pragma unroll
        for (int ks = 0; ks < 2; ++ks) {
            short8 af[2];
            #pragma unroll
            for (int si = 0; si < 2; ++si) {
                const int s = 2 * w + si;
                const int c = (ks * 4 + fg) ^ (fr & 7);
                af[si] = *(const short8*)((const char*)&att[s][fr][0] + c * 16);
            }
            #pragma unroll
            for (int n = 0; n < 4; ++n) {
                #pragma unroll
                for (int si = 0; si < 2; ++si) {
                    const int bs = b * 8 + 2 * w + si;
                    const short8 bf = *(const short8*)(
                        hT + ((size_t)bs << 16) + (size_t)(n * 16 + fr) * N_ + j0 + ks * 32 + fg * 8);
                    acc[si][n] = __builtin_amdgcn_mfma_f32_16x16x32_bf16(af[si], bf, acc[si][n], 0, 0, 0);
                }
            }
        }
        __syncthreads();
    }

    // ---- epilogue: write bf16 partials (no elu) ----
    #pragma unroll
    for (int si = 0; si < 2; ++si) {
        const int bs = b * 8 + 2 * w + si;
        #pragma unroll
        for (int n = 0; n < 4; ++n) {
            #pragma unroll
            for (int r = 0; r < 4; ++r) {
                part[(size_t)kk * H_ELEMS + ((size_t)bs << 16)
                     + (size_t)(i0 + fg * 4 + r) * FO + n * 16 + fr] = f2bf(acc[si][n][r]);
            }
        }
    }
}

// ---------------- Kernel 4: combine 8 bf16 partials + elu -------------------
__global__ __launch_bounds__(256) void k_comb(
    const unsigned short* __restrict__ part, float* __restrict__ out_h)
{
    const size_t idx = ((size_t)blockIdx.x * 256 + threadIdx.x) * 8;
    float acc[8] = {0.f,0.f,0.f,0.f,0.f,0.f,0.f,0.f};
    #pragma unroll
    for (int p = 0; p < SPLITK; ++p) {
        const uint4 v = *(const uint4*)(part + (size_t)p * H_ELEMS + idx);
        acc[0] += bf2f_lo(v.x); acc[1] += bf2f_hi(v.x);
        acc[2] += bf2f_lo(v.y); acc[3] += bf2f_hi(v.y);
        acc[4] += bf2f_lo(v.z); acc[5] += bf2f_hi(v.z);
        acc[6] += bf2f_lo(v.w); acc[7] += bf2f_hi(v.w);
    }
    float4 r0, r1;
    r0.x = acc[0] > 0.f ? acc[0] : expm1f(acc[0]);
    r0.y = acc[1] > 0.f ? acc[1] : expm1f(acc[1]);
    r0.z = acc[2] > 0.f ? acc[2] : expm1f(acc[2]);
    r0.w = acc[3] > 0.f ? acc[3] : expm1f(acc[3]);
    r1.x = acc[4] > 0.f ? acc[4] : expm1f(acc[4]);
    r1.y = acc[5] > 0.f ? acc[5] : expm1f(acc[5]);
    r1.z = acc[6] > 0.f ? acc[6] : expm1f(acc[6]);
    r1.w = acc[7] > 0.f ? acc[7] : expm1f(acc[7]);
    *(float4*)(out_h + idx) = r0;
    *(float4*)(out_h + idx + 4) = r1;
}

extern "C" void kernel_launch(void* const* d_in, const int* in_sizes, int n_in,
                              void* d_out, int out_size, void* d_ws, size_t ws_size,
                              hipStream_t stream)
{
    const float* x   = (const float*)d_in[0];
    const int*   Adj = (const int*)d_in[1];
    const float* W   = (const float*)d_in[2];
    const float* a   = (const float*)d_in[3];

    float* out = (float*)d_out;
    float* ws  = (float*)d_ws;

    // ws layout (f32 slots): f1 | f2 | hT(bf16) | h(f32) / part(bf16, aliased)
    float* f1 = ws;                                   // 32,768
    float* f2 = f1 + F_ELEMS;                         // 32,768
    unsigned short* hT = (unsigned short*)(f2 + F_ELEMS);   // H_ELEMS bf16 (4 MB)
    float* h = f2 + F_ELEMS + H_ELEMS / 2;            // 8 MB f32 (dead after k_tr)
    unsigned short* part = (unsigned short*)h;        // 8*H_ELEMS bf16 = 32 MB

    float* out_h   = out;                             // elu(h_prime)
    float* out_adj = out + H_ELEMS;                   // Adj as float

    hipLaunchKernelGGL(k_h,    dim3(BS * N_ / 4),           dim3(256), 0, stream, x, W, a, h, f1, f2);
    hipLaunchKernelGGL(k_tr,   dim3(BS * 16),               dim3(256), 0, stream, h, hT);
    hipLaunchKernelGGL(k_av,   dim3(SPLITK * 4 * 64),       dim3(256), 0, stream, Adj, f1, f2, hT, part, out_adj);
    hipLaunchKernelGGL(k_comb, dim3((int)(H_ELEMS / 2048)), dim3(256), 0, stream, part, out_h);
}